// Round 1
// 132.231 us; speedup vs baseline: 1.0044x; 1.0044x over previous
//
#include <hip/hip_runtime.h>
#include <stdint.h>

// Problem constants (match reference)
constexpr int B = 4, C = 16, H = 512, W = 512;
constexpr int N = H * W;                   // pixels per batch plane (262144)
constexpr int BLOCKS_PER_BATCH = N / 256;  // 1024
constexpr int NXCD = 8;
constexpr float EPS = 1e-10f;

// Three-phase scatter (racy store + pruned atomic fixup + resolve).
// R6 structure (133.5us) + phase-A store elision (132.8us measured).
// This round: XCD-contiguous slab swizzle for phases A and B.
//   Default dispatch round-robins blocks across the 8 XCDs, so adjacent
//   image rows sit on different XCDs and the random 8B keys scatter makes
//   all 8 non-coherent L2s hold partial dirty copies of the same 64B
//   lines (fetch+writeback amplification, L3-side merging). Remapping so
//   each XCD owns a contiguous 64-row slab per batch keeps ~all scattered
//   stores (displacement ~ +-30 rows) inside that XCD's own L2 slab.
// R8 lesson: cooperative grid.sync() costs ~100 us/sync on gfx950 —
// split kernels ARE the efficient grid barrier. R10: nontemporal loads
// regress. d_ws poison (0xAA): hi = 0xAAAAAAAA > N-1 marks untouched.

__device__ __forceinline__ void swizzle_bn(int orig, int tid, int& b, int& n) {
    // Assumes round-robin block->XCD dispatch (orig % 8 == XCD) — a perf
    // heuristic only; correctness is mapping-independent (bijection).
    int xcd = orig & (NXCD - 1);
    int j   = orig >> 3;               // 0..511
    b       = j >> 7;                  // 0..3  (batch)
    int r   = j & 127;                 // 0..127 (block within slab)
    int blk = xcd * 128 + r;           // 0..1023 (block within batch)
    n = (blk << 8) + tid;              // pixel within batch plane
}

__global__ __launch_bounds__(256) void project_store_kernel(
    const float* __restrict__ depth,   // [B,1,H,W]
    const float* __restrict__ K,       // [B,3,3]
    const float* __restrict__ T,       // [B,C,4,4]
    const int*   __restrict__ masks,   // [B,C,H,W] (0/1)
    unsigned long long* __restrict__ keys, // [B,N] u64, poison-initialized
    unsigned long long* __restrict__ recs) // [B,N] u64 per-source (t<<32)|z
{
    __shared__ float Ts[16][17];       // Ts[e][c] = T[b][c][e]

    int b, n;
    swizzle_bn(blockIdx.x, threadIdx.x, b, n);
    int idx = b * N + n;
    int v = n >> 9;                    // n / W
    int u = n & (W - 1);               // n % W
    int lane = threadIdx.x & 63;

    // stage T[b] (256 floats) into LDS, transposed
    {
        int t = threadIdx.x;           // t = c*16 + e
        int c = t >> 4, e = t & 15;
        Ts[e][c] = T[(size_t)b * 256 + t];
    }
    __syncthreads();

    float d = depth[idx];

    // --- K[b] (block-uniform scalar loads) ---
    const float* Kb = K + b * 9;
    float k00 = Kb[0], k01 = Kb[1], k02 = Kb[2];
    float k10 = Kb[3], k11 = Kb[4], k12 = Kb[5];
    float k20 = Kb[6], k21 = Kb[7], k22 = Kb[8];

    // adjugate inverse
    float c00 =  (k11 * k22 - k12 * k21);
    float c01 = -(k10 * k22 - k12 * k20);
    float c02 =  (k10 * k21 - k11 * k20);
    float det = k00 * c00 + k01 * c01 + k02 * c02;
    float invdet = 1.0f / det;
    float i00 =  (k11 * k22 - k12 * k21) * invdet;
    float i01 = -(k01 * k22 - k02 * k21) * invdet;
    float i02 =  (k01 * k12 - k02 * k11) * invdet;
    float i10 = -(k10 * k22 - k12 * k20) * invdet;
    float i11 =  (k00 * k22 - k02 * k20) * invdet;
    float i12 = -(k00 * k12 - k02 * k10) * invdet;
    float i20 =  (k10 * k21 - k11 * k20) * invdet;
    float i21 = -(k00 * k21 - k01 * k20) * invdet;
    float i22 =  (k00 * k11 - k01 * k10) * invdet;

    float uf = (float)u, vf = (float)v;
    float px = (i00 * uf + i01 * vf + i02) * d;
    float py = (i10 * uf + i11 * vf + i12) * d;
    float pz = (i20 * uf + i21 * vf + i22) * d;

    // --- mask scan: 4-channel tiers from the top (expected 1.07 tiers) ---
    const int* mb = masks + (size_t)b * C * N + n;
    int sel;
    {
        int m3 = mb[(size_t)15 * N], m2 = mb[(size_t)14 * N];
        int m1 = mb[(size_t)13 * N], m0 = mb[(size_t)12 * N];
        sel = m3 ? 15 : m2 ? 14 : m1 ? 13 : m0 ? 12 : -1;
        if (sel < 0) {
            m3 = mb[(size_t)11 * N]; m2 = mb[(size_t)10 * N];
            m1 = mb[(size_t)9 * N];  m0 = mb[(size_t)8 * N];
            sel = m3 ? 11 : m2 ? 10 : m1 ? 9 : m0 ? 8 : -1;
        }
        if (sel < 0) {
            m3 = mb[(size_t)7 * N]; m2 = mb[(size_t)6 * N];
            m1 = mb[(size_t)5 * N]; m0 = mb[(size_t)4 * N];
            sel = m3 ? 7 : m2 ? 6 : m1 ? 5 : m0 ? 4 : -1;
        }
        if (sel < 0) {
            m3 = mb[(size_t)3 * N]; m2 = mb[(size_t)2 * N];
            m1 = mb[(size_t)1 * N]; m0 = mb[0];
            sel = m3 ? 3 : m2 ? 2 : m1 ? 1 : m0 ? 0 : -1;
        }
    }

    float ox = px, oy = py, oz = pz;
    if (sel >= 0) {
        float tx = Ts[0][sel]  * px + Ts[1][sel]  * py + Ts[2][sel]  * pz + Ts[3][sel];
        float ty = Ts[4][sel]  * px + Ts[5][sel]  * py + Ts[6][sel]  * pz + Ts[7][sel];
        float tz = Ts[8][sel]  * px + Ts[9][sel]  * py + Ts[10][sel] * pz + Ts[11][sel];
        float tw = Ts[12][sel] * px + Ts[13][sel] * py + Ts[14][sel] * pz + Ts[15][sel];
        float denom = tw + EPS;
        ox = tx / denom;
        oy = ty / denom;
        oz = tz / denom;
    }

    // --- reproject with K ---
    float qx = k00 * ox + k01 * oy + k02 * oz;
    float qy = k10 * ox + k11 * oy + k12 * oz;
    float qz = k20 * ox + k21 * oy + k22 * oz;
    float zz = qz + EPS;
    float pu = qx / zz;
    float pv = qy / zz;
    pu = fminf(fmaxf(pu, 0.0f), (float)(W - 1));
    pv = fminf(fmaxf(pv, 0.0f), (float)(H - 1));
    int ui = (int)pu;
    int vi = (int)pv;
    unsigned t = (unsigned)(vi * W + ui);
    unsigned zbits = __float_as_uint(oz);

    recs[idx] = ((unsigned long long)t << 32) | (unsigned long long)zbits;

    // +-4 domination window: a same-cell contender with strictly larger n
    // in this wave makes our store irrelevant — elide it.
    bool dom = false;
    #pragma unroll
    for (int delta = 1; delta <= 4; ++delta) {
        unsigned tn = (unsigned)__shfl_down((int)t, delta);
        dom |= (lane + delta < 64) && (tn == t);
    }
    if (!dom) {
        keys[(size_t)b * N + t] =
            ((unsigned long long)(unsigned)n << 32) | (unsigned long long)zbits;
    }
}

// Phase B: fixup — wave-neighbor pruning, then atomic only where needed.
// Same swizzle as phase A so each XCD re-gathers its own keys slab.
__global__ __launch_bounds__(256) void fixup_kernel(
    unsigned long long* __restrict__ keys,
    const unsigned long long* __restrict__ recs)
{
    int b, n;
    swizzle_bn(blockIdx.x, threadIdx.x, b, n);
    int idx = b * N + n;
    int lane = threadIdx.x & 63;

    unsigned long long rec = recs[idx];
    unsigned t = (unsigned)(rec >> 32);
    unsigned zbits = (unsigned)rec;

    bool dom = false;
    #pragma unroll
    for (int delta = 1; delta <= 4; ++delta) {
        unsigned tn = (unsigned)__shfl_down((int)t, delta);
        dom |= (lane + delta < 64) && (tn == t);
    }
    if (dom) return;   // a larger contender guarantees the cell's final value

    unsigned long long* cell = &keys[(size_t)b * N + t];
    unsigned hi = (unsigned)(*cell >> 32);
    // Observed value is poison or some contender's key (monotone post-A).
    // hi >= n (and not poison) => final >= key(n) already guaranteed.
    if (hi > (unsigned)(N - 1) || hi < (unsigned)n) {
        unsigned long long key =
            ((unsigned long long)(unsigned)n << 32) | (unsigned long long)zbits;
        atomicMax(cell, key);
    }
}

// Phase C: resolve — winner's Z where touched, else original depth.
__global__ __launch_bounds__(256) void resolve_kernel(
    const unsigned long long* __restrict__ keys,
    const float*              __restrict__ depth,
    float*                    __restrict__ out)
{
    int idx = blockIdx.x * blockDim.x + threadIdx.x;
    if (idx >= B * N) return;
    unsigned long long k = keys[idx];
    unsigned hi = (unsigned)(k >> 32);
    out[idx] = (hi <= (unsigned)(N - 1)) ? __uint_as_float((unsigned)k)
                                         : depth[idx];
}

extern "C" void kernel_launch(void* const* d_in, const int* in_sizes, int n_in,
                              void* d_out, int out_size, void* d_ws, size_t ws_size,
                              hipStream_t stream) {
    const float* depth = (const float*)d_in[0];   // [B,1,H,W] fp32
    const float* K     = (const float*)d_in[1];   // [B,3,3]   fp32
    const float* T     = (const float*)d_in[2];   // [B,C,4,4] fp32
    const int*   masks = (const int*)d_in[3];     // [B,C,H,W] int32 0/1
    float* out = (float*)d_out;                    // [B,1,H,W] fp32

    char* ws = (char*)d_ws;
    unsigned long long* keys = (unsigned long long*)ws;                 // 8 MB
    unsigned long long* recs = (unsigned long long*)(ws + (size_t)B * N * 8); // 8 MB

    int grid = B * BLOCKS_PER_BATCH;   // 4096 blocks of 256
    project_store_kernel<<<grid, 256, 0, stream>>>(depth, K, T, masks, keys, recs);
    fixup_kernel<<<grid, 256, 0, stream>>>(keys, recs);
    resolve_kernel<<<grid, 256, 0, stream>>>(keys, depth, out);
}